// Round 6
// baseline (638.685 us; speedup 1.0000x reference)
//
#include <hip/hip_runtime.h>
#include <math.h>

namespace {
constexpr int cB  = 8;
constexpr int cN  = 4096;
constexpr int cC  = 768;
constexpr int cH  = 12;
constexpr int cHD = 64;
constexpr int cM  = 32;
}

typedef __attribute__((ext_vector_type(8))) short bf16x8;
typedef __attribute__((ext_vector_type(4))) float f32x4;
typedef __attribute__((ext_vector_type(16))) float f32x16;

#define BARRIER() do { asm volatile("" ::: "memory"); __builtin_amdgcn_s_barrier(); asm volatile("" ::: "memory"); } while (0)
#define WAIT_VM(N) do { asm volatile("s_waitcnt vmcnt(" #N ")" ::: "memory"); __builtin_amdgcn_sched_barrier(0); } while (0)

__device__ __forceinline__ void async_copy16(const void* g, void* l) {
    __builtin_amdgcn_global_load_lds((const __attribute__((address_space(1))) void*)g,
                                     (__attribute__((address_space(3))) void*)l, 16, 0, 0);
}

__device__ __forceinline__ ushort f32_to_bf16_rne(float x) {
    unsigned int u = __float_as_uint(x);
    u += 0x7fffu + ((u >> 16) & 1u);
    return (ushort)(u >> 16);
}

__device__ __forceinline__ float bf16_to_f32(ushort u) {
    return __uint_as_float(((unsigned)u) << 16);
}

// RNE split: f ~= hi + lo, unbiased
__device__ __forceinline__ void split2(float f, ushort& h, ushort& l) {
    h = f32_to_bf16_rne(f);
    float r = f - bf16_to_f32(h);
    l = f32_to_bf16_rne(r);
}

__global__ __launch_bounds__(256)
void split_bf16(const float* __restrict__ in, ushort* __restrict__ hi,
                ushort* __restrict__ lo, int n4)
{
    int i = blockIdx.x * 256 + threadIdx.x;
    const int stride = gridDim.x * 256;
    for (; i < n4; i += stride) {
        float4 v = reinterpret_cast<const float4*>(in)[i];
        ushort4 h, l;
        split2(v.x, h.x, l.x);
        split2(v.y, h.y, l.y);
        split2(v.z, h.z, l.z);
        split2(v.w, h.w, l.w);
        reinterpret_cast<ushort4*>(hi)[i] = h;
        reinterpret_cast<ushort4*>(lo)[i] = l;
    }
}

// 256x256-tile GEMM, 32x32x16 MFMA, BK=16, 4-deep circular LDS staging with
// counted vmcnt (never 0 in steady state).  C = sum_terms Ap*Bp^T + bias.
// TERMS=3: Ah*Bh+Ah*Bl+Al*Bh;  TERMS=1: Ah*Bh.
// mode 0: Cf fp32 [M,Ndim]; mode 2: Cb bf16 v-permuted [b,h,t,d].
// Plane layout [256][16] bf16 (32B rows): wave-frag reads hit the structural
// bank minimum (8/bank) -> no swizzle needed; staging stays linear.
template <int TERMS>
__global__ __launch_bounds__(512, 2)
void gemm256(const ushort* __restrict__ Ah, const ushort* __restrict__ Al,
             const ushort* __restrict__ Bh, const ushort* __restrict__ Bl,
             const float* __restrict__ bias,
             float* __restrict__ Cf, ushort* __restrict__ Cb,
             int Ndim, int K, int mode)
{
    constexpr int NPL = (TERMS == 3) ? 4 : 2;       // planes per tile
    __shared__ ushort smem[4 * NPL * 4096];         // 4 bufs x planes x [256][16]
    const int tid = threadIdx.x;
    const int wave = tid >> 6, lane = tid & 63;
    const int wm = wave >> 2, wn = wave & 3;        // 2M x 4N waves, 128x64 each
    const int l31 = lane & 31, kh = (lane >> 5) * 8;

    // XCD-chunked swizzle (gridDim.y == 128 for all uses; nwg % 8 == 0)
    const int nwg = gridDim.x * 128;
    const int orig = blockIdx.x * 128 + blockIdx.y;
    const int swz = (orig & 7) * (nwg >> 3) + (orig >> 3);
    const int row0 = (swz & 127) << 8;
    const int col0 = (swz >> 7) << 8;

    const ushort* planes[NPL];
    planes[0] = Ah;
    if constexpr (TERMS == 3) { planes[1] = Al; planes[2] = Bh; planes[3] = Bl; }
    else                      { planes[1] = Bh; }

    // staging: thread tid stages 16B chunk: row=tid>>1, kc=tid&1; LDS offset
    // tid*8 ushorts == row*16 + kc*8 (linear == row-major [256][16])
    const int srow = tid >> 1;
    const int skc = (tid & 1) * 8;
    const ushort* gsrc[NPL];
    #pragma unroll
    for (int p = 0; p < NPL; ++p) {
        const int grow = ((p < NPL / 2) ? row0 : col0) + srow;
        gsrc[p] = planes[p] + (size_t)grow * K + skc;
    }
    const int sdst = tid * 8;

    const int NT = K >> 4;
    f32x16 acc[4][2] = {};

    // prologue: issue tiles 0,1,2; wait tile 0 (outstanding <= 2*NPL)
    #pragma unroll
    for (int tt = 0; tt < 3; ++tt)
        #pragma unroll
        for (int p = 0; p < NPL; ++p)
            async_copy16(gsrc[p] + tt * 16, &smem[(tt * NPL + p) * 4096 + sdst]);
    if constexpr (NPL == 4) WAIT_VM(8); else WAIT_VM(4);
    BARRIER();

    for (int t = 0; t < NT; ++t) {
        const int cbuf = (t & 3) * NPL * 4096;
        // issue tile t+3 (writes buf (t-1)%4: all readers done at end-of-(t-1) barrier)
        if (t + 3 < NT) {
            const int nbuf = ((t + 3) & 3) * NPL * 4096;
            #pragma unroll
            for (int p = 0; p < NPL; ++p)
                async_copy16(gsrc[p] + (t + 3) * 16, &smem[nbuf + p * 4096 + sdst]);
        }
        // fragment reads (compiler inserts lgkmcnt before dependent MFMA)
        bf16x8 fb[2][2], fa[4][2];
        #pragma unroll
        for (int nt = 0; nt < 2; ++nt) {
            const int base = cbuf + (NPL / 2) * 4096 + (wn * 64 + nt * 32 + l31) * 16 + kh;
            fb[nt][0] = *reinterpret_cast<const bf16x8*>(&smem[base]);
            if constexpr (TERMS == 3)
                fb[nt][1] = *reinterpret_cast<const bf16x8*>(&smem[base + 4096]);
        }
        #pragma unroll
        for (int mt = 0; mt < 4; ++mt) {
            const int base = cbuf + (wm * 128 + mt * 32 + l31) * 16 + kh;
            fa[mt][0] = *reinterpret_cast<const bf16x8*>(&smem[base]);
            if constexpr (TERMS == 3)
                fa[mt][1] = *reinterpret_cast<const bf16x8*>(&smem[base + 4096]);
        }
        __builtin_amdgcn_s_setprio(1);
        #pragma unroll
        for (int mt = 0; mt < 4; ++mt)
            #pragma unroll
            for (int nt = 0; nt < 2; ++nt)
                acc[mt][nt] = __builtin_amdgcn_mfma_f32_32x32x16_bf16(fa[mt][0], fb[nt][0], acc[mt][nt], 0, 0, 0);
        if constexpr (TERMS == 3) {
            #pragma unroll
            for (int mt = 0; mt < 4; ++mt)
                #pragma unroll
                for (int nt = 0; nt < 2; ++nt)
                    acc[mt][nt] = __builtin_amdgcn_mfma_f32_32x32x16_bf16(fa[mt][0], fb[nt][1], acc[mt][nt], 0, 0, 0);
            #pragma unroll
            for (int mt = 0; mt < 4; ++mt)
                #pragma unroll
                for (int nt = 0; nt < 2; ++nt)
                    acc[mt][nt] = __builtin_amdgcn_mfma_f32_32x32x16_bf16(fa[mt][1], fb[nt][0], acc[mt][nt], 0, 0, 0);
        }
        __builtin_amdgcn_s_setprio(0);
        // boundary: ensure tile t+1 landed; counted, never 0 until the tail
        const int rem = NT - 2 - t;
        if (rem >= 2)      { if constexpr (NPL == 4) WAIT_VM(8); else WAIT_VM(4); }
        else if (rem == 1) { if constexpr (NPL == 4) WAIT_VM(4); else WAIT_VM(2); }
        else if (rem == 0) WAIT_VM(0);
        BARRIER();
    }

    // epilogue: C/D 32x32 layout col=lane&31, row=(reg&3)+8*(reg>>2)+4*(lane>>5)
    #pragma unroll
    for (int nt = 0; nt < 2; ++nt) {
        const int c = col0 + wn * 64 + nt * 32 + l31;
        const float bv = bias[c];
        #pragma unroll
        for (int mt = 0; mt < 4; ++mt) {
            #pragma unroll
            for (int reg = 0; reg < 16; ++reg) {
                const int rr = (reg & 3) + 8 * (reg >> 2) + 4 * (lane >> 5);
                const int row = row0 + wm * 128 + mt * 32 + rr;
                const float val = acc[mt][nt][reg] + bv;
                if (mode == 0) {
                    Cf[(size_t)row * Ndim + c] = val;
                } else {
                    const int b = row >> 12, tt = row & 4095;
                    const int h = c >> 6, d = c & 63;
                    Cb[(((size_t)(b * cH + h) * cN + tt) << 6) + d] = f32_to_bf16_rne(val);
                }
            }
        }
    }
}

// Performer feature map via register-direct MFMA. One wave per (bh, 64-t block).
__global__ __launch_bounds__(64)
void prm_exp_mfma(const float* __restrict__ kq, const ushort* __restrict__ wh,
                  const ushort* __restrict__ wl, ushort* __restrict__ phi,
                  float* __restrict__ kpsum_p, int col_off, int do_sum)
{
    const int bh = blockIdx.x, tblk = blockIdx.y;
    const int b = bh / cH, h = bh % cH;
    const int t0 = tblk * 64;
    const int lane = threadIdx.x;
    const int fr = lane & 15, fk = lane >> 4;

    bf16x8 Bh2[2][2], Bl2[2][2];
    #pragma unroll
    for (int mf = 0; mf < 2; ++mf)
        #pragma unroll
        for (int kc = 0; kc < 2; ++kc) {
            size_t off = (size_t)(h * 32 + mf * 16 + fr) * 64 + kc * 32 + fk * 8;
            Bh2[mf][kc] = *reinterpret_cast<const bf16x8*>(&wh[off]);
            Bl2[mf][kc] = *reinterpret_cast<const bf16x8*>(&wl[off]);
        }

    f32x4 acc[4][2] = {};
    float xdv4[4];
    #pragma unroll
    for (int tf = 0; tf < 4; ++tf) {
        const float* krow = &kq[(size_t)(b * cN + t0 + tf * 16 + fr) * 1536 + col_off + h * 64];
        float4 f0 = *reinterpret_cast<const float4*>(&krow[fk * 8]);
        float4 f1 = *reinterpret_cast<const float4*>(&krow[fk * 8 + 4]);
        float4 f2 = *reinterpret_cast<const float4*>(&krow[32 + fk * 8]);
        float4 f3 = *reinterpret_cast<const float4*>(&krow[32 + fk * 8 + 4]);
        float xs = f0.x*f0.x + f0.y*f0.y + f0.z*f0.z + f0.w*f0.w
                 + f1.x*f1.x + f1.y*f1.y + f1.z*f1.z + f1.w*f1.w
                 + f2.x*f2.x + f2.y*f2.y + f2.z*f2.z + f2.w*f2.w
                 + f3.x*f3.x + f3.y*f3.y + f3.z*f3.z + f3.w*f3.w;
        xs += __shfl_xor(xs, 16);
        xs += __shfl_xor(xs, 32);
        xdv4[tf] = 0.5f * xs;
        bf16x8 Ah2[2], Al2[2];
        {
            float fa[8] = {f0.x,f0.y,f0.z,f0.w,f1.x,f1.y,f1.z,f1.w};
            float fb[8] = {f2.x,f2.y,f2.z,f2.w,f3.x,f3.y,f3.z,f3.w};
            #pragma unroll
            for (int j = 0; j < 8; ++j) {
                ushort hh, ll;
                split2(fa[j], hh, ll); Ah2[0][j] = (short)hh; Al2[0][j] = (short)ll;
                split2(fb[j], hh, ll); Ah2[1][j] = (short)hh; Al2[1][j] = (short)ll;
            }
        }
        #pragma unroll
        for (int kc = 0; kc < 2; ++kc)
            #pragma unroll
            for (int mf = 0; mf < 2; ++mf) {
                acc[tf][mf] = __builtin_amdgcn_mfma_f32_16x16x32_bf16(Ah2[kc], Bh2[mf][kc], acc[tf][mf], 0, 0, 0);
                acc[tf][mf] = __builtin_amdgcn_mfma_f32_16x16x32_bf16(Ah2[kc], Bl2[mf][kc], acc[tf][mf], 0, 0, 0);
                acc[tf][mf] = __builtin_amdgcn_mfma_f32_16x16x32_bf16(Al2[kc], Bh2[mf][kc], acc[tf][mf], 0, 0, 0);
            }
    }

    const float rsm = 0.17677669529663687f;  // 1/sqrt(32)
    float sm0 = 0.f, sm1 = 0.f;
    #pragma unroll
    for (int tf = 0; tf < 4; ++tf) {
        #pragma unroll
        for (int j = 0; j < 4; ++j) {
            const int rloc = (lane >> 4) * 4 + j;
            const float xdv = __shfl(xdv4[tf], (lane & 48) | rloc);
            const int t = t0 + tf * 16 + rloc;
            float e0 = __expf(acc[tf][0][j] - xdv) * rsm;
            float e1 = __expf(acc[tf][1][j] - xdv) * rsm;
            phi[((size_t)bh * cN + t) * cM + fr]      = f32_to_bf16_rne(e0);
            phi[((size_t)bh * cN + t) * cM + 16 + fr] = f32_to_bf16_rne(e1);
            sm0 += e0; sm1 += e1;
        }
    }
    if (do_sum) {
        sm0 += __shfl_xor(sm0, 16); sm0 += __shfl_xor(sm0, 32);
        sm1 += __shfl_xor(sm1, 16); sm1 += __shfl_xor(sm1, 32);
        if (lane < 16) {
            kpsum_p[((size_t)bh * 64 + tblk) * cM + lane]      = sm0;
            kpsum_p[((size_t)bh * 64 + tblk) * cM + 16 + lane] = sm1;
        }
    }
}

// kptv partials: kptv_p[c][bh][d][m] over 32-t slices; c = chunk*2+half, 16 total
__global__ __launch_bounds__(256, 4)
void kptv_part(const ushort* __restrict__ vbf, const ushort* __restrict__ kp,
               float* __restrict__ kptv_p)
{
    const int bh = blockIdx.x, chunk = blockIdx.y;
    __shared__ float vl[64][68];
    __shared__ float kl[64][36];
    const int tid = threadIdx.x;
    const int half = tid >> 7;
    const int dg = (tid >> 3) & 15;
    const int mg = tid & 7;
    float acc[4][4] = {};
    for (int tile = 0; tile < 8; ++tile) {
        const int tb = chunk * 512 + tile * 64;
        #pragma unroll
        for (int i = 0; i < 2; ++i) {
            int idx = i * 256 + tid;
            int row = idx >> 3, seg = idx & 7;
            bf16x8 vv = *reinterpret_cast<const bf16x8*>(&vbf[((size_t)bh * cN + tb + row) * 64 + seg * 8]);
            float4 lo4 = make_float4(bf16_to_f32((ushort)vv[0]), bf16_to_f32((ushort)vv[1]),
                                     bf16_to_f32((ushort)vv[2]), bf16_to_f32((ushort)vv[3]));
            float4 hi4 = make_float4(bf16_to_f32((ushort)vv[4]), bf16_to_f32((ushort)vv[5]),
                                     bf16_to_f32((ushort)vv[6]), bf16_to_f32((ushort)vv[7]));
            *reinterpret_cast<float4*>(&vl[row][seg * 8])     = lo4;
            *reinterpret_cast<float4*>(&vl[row][seg * 8 + 4]) = hi4;
        }
        {
            int row = tid >> 2, seg = tid & 3;
            bf16x8 vv = *reinterpret_cast<const bf16x8*>(&kp[((size_t)bh * cN + tb + row) * 32 + seg * 8]);
            float4 lo4 = make_float4(bf16_to_f32((ushort)vv[0]), bf16_to_f32((ushort)vv[1]),
                                     bf16_to_f32((ushort)vv[2]), bf16_to_f32((ushort)vv[3]));
            float4 hi4 = make_float4(bf16_to_f32((ushort)vv[4]), bf16_to_f32((ushort)vv[5]),
                                     bf16_to_f32((ushort)vv[6]), bf16_to_f32((ushort)vv[7]));
            *reinterpret_cast<float4*>(&kl[row][seg * 8])     = lo4;
            *reinterpret_cast<float4*>(&kl[row][seg * 8 + 4]) = hi4;
        }
        __syncthreads();
        for (int t = 0; t < 32; ++t) {
            const int tt = half * 32 + t;
            float4 av = *reinterpret_cast<const float4*>(&vl[tt][dg * 4]);
            float4 bv = *reinterpret_cast<const float4*>(&kl[tt][mg * 4]);
            float a4[4] = {av.x, av.y, av.z, av.w};
            float b4[4] = {bv.x, bv.y, bv.z, bv.w};
            #pragma unroll
            for (int i = 0; i < 4; ++i)
                #pragma unroll
                for (int j = 0; j < 4; ++j)
                    acc[i][j] = fmaf(a4[i], b4[j], acc[i][j]);
        }
        __syncthreads();
    }
    float* outp = &kptv_p[(((size_t)chunk * 2 + half) * 96 + bh) * 2048];
    #pragma unroll
    for (int i = 0; i < 4; ++i)
        *reinterpret_cast<float4*>(&outp[(dg * 4 + i) * 32 + mg * 4]) =
            make_float4(acc[i][0], acc[i][1], acc[i][2], acc[i][3]);
}

// reduce partials -> kptvx bf16 [bh][80][32]: rows 0..63 kptv, row 64 kpsum, 65..79 zero
__global__ __launch_bounds__(256)
void kptv_reduce(const float* __restrict__ kptv_p, const float* __restrict__ kpsum_p,
                 ushort* __restrict__ kptvx)
{
    const int bh = blockIdx.x, tid = threadIdx.x;
    for (int l = tid; l < 2048; l += 256) {
        float s = 0.f;
        #pragma unroll
        for (int c = 0; c < 16; ++c) s += kptv_p[((size_t)c * 96 + bh) * 2048 + l];
        kptvx[(size_t)bh * 2560 + l] = f32_to_bf16_rne(s);
    }
    if (tid < 32) {
        float s = 0.f;
        #pragma unroll
        for (int c = 0; c < 64; ++c) s += kpsum_p[((size_t)bh * 64 + c) * cM + tid];
        kptvx[(size_t)bh * 2560 + 64 * 32 + tid] = f32_to_bf16_rne(s);
    }
    for (int l = tid; l < 480; l += 256)
        kptvx[(size_t)bh * 2560 + 65 * 32 + l] = 0;
}

// y = (qp . kptv) / (qp . kpsum + eps) via one MFMA pass (D appended as B-row 64)
__global__ __launch_bounds__(64)
void pv_mfma(const ushort* __restrict__ qp, const ushort* __restrict__ kptvx,
             ushort* __restrict__ yh, ushort* __restrict__ yl)
{
    const int bh = blockIdx.x, tblk = blockIdx.y;
    const int b = bh / cH, h = bh % cH;
    const int t0 = tblk * 64;
    const int lane = threadIdx.x;
    const int fr = lane & 15, fk = lane >> 4;
    bf16x8 Bf[5];
    #pragma unroll
    for (int nf = 0; nf < 5; ++nf)
        Bf[nf] = *reinterpret_cast<const bf16x8*>(&kptvx[(size_t)bh * 2560 + (nf * 16 + fr) * 32 + fk * 8]);
    f32x4 acc[4][5] = {};
    #pragma unroll
    for (int tf = 0; tf < 4; ++tf) {
        bf16x8 Af = *reinterpret_cast<const bf16x8*>(&qp[((size_t)bh * cN + t0 + tf * 16 + fr) * cM + fk * 8]);
        #pragma unroll
        for (int nf = 0; nf < 5; ++nf)
            acc[tf][nf] = __builtin_amdgcn_mfma_f32_16x16x32_bf16(Af, Bf[nf], acc[tf][nf], 0, 0, 0);
    }
    #pragma unroll
    for (int tf = 0; tf < 4; ++tf) {
        #pragma unroll
        for (int j = 0; j < 4; ++j) {
            const int rloc = (lane >> 4) * 4 + j;
            const int t = t0 + tf * 16 + rloc;
            const float Dv = __shfl(acc[tf][4][j], lane & 48) + 1e-8f;
            const float rD = 1.0f / Dv;
            #pragma unroll
            for (int nf = 0; nf < 4; ++nf) {
                float yv = acc[tf][nf][j] * rD;
                ushort hh, ll; split2(yv, hh, ll);
                size_t oa = (size_t)(b * cN + t) * cC + h * 64 + nf * 16 + fr;
                yh[oa] = hh; yl[oa] = ll;
            }
        }
    }
}

extern "C" void kernel_launch(void* const* d_in, const int* in_sizes, int n_in,
                              void* d_out, int out_size, void* d_ws, size_t ws_size,
                              hipStream_t stream)
{
    const float* x      = (const float*)d_in[0];
    const float* kqv_w  = (const float*)d_in[1];
    const float* kqv_b  = (const float*)d_in[2];
    const float* proj_w = (const float*)d_in[3];
    const float* proj_b = (const float*)d_in[4];
    const float* w      = (const float*)d_in[5];

    char* wsb = (char*)d_ws;
    float*  kq   = (float*)(wsb);                  // [32768,1536] fp32, 201,326,592 B
    ushort* yh   = (ushort*)(wsb);                 // aliases kq after dead
    ushort* yl   = (ushort*)(wsb + 50331648);
    ushort* vbf  = (ushort*)(wsb + 201326592);     // [96][4096][64] bf16
    ushort* wh   = (ushort*)(wsb + 251658240);     // kqv_w hi
    ushort* wl_  = (ushort*)(wsb + 255197184);     // kqv_w lo
    ushort* pwh  = (ushort*)(wsb + 258736128);     // proj_w hi
    ushort* pwl  = (ushort*)(wsb + 259915776);     // proj_w lo
    ushort* whb  = (ushort*)(wsb + 261095424);     // w hi (bf16)
    ushort* wlb  = (ushort*)(wsb + 261144576);     // w lo

    char* ob = (char*)d_out;
    ushort* xh      = (ushort*)ob;                 // x hi plane
    ushort* xl      = (ushort*)(ob + 50331648);    // x lo plane
    ushort* kp      = (ushort*)ob;                 // [96][4096][32] bf16 (after xh dead)
    ushort* qp      = (ushort*)(ob + 25165824);
    float*  kptv_p  = (float*)(ob + 50331648);     // [16][96][2048] fp32 (after xl dead)
    float*  kpsum_p = (float*)(ob + 62914560);     // [96][64][32] fp32
    ushort* kptvx   = (ushort*)(ob + 63700992);    // [96][80][32] bf16
    float*  out     = (float*)d_out;

    dim3 blk(256);
    // splits (RNE hi/lo planes)
    split_bf16<<<2048, blk, 0, stream>>>(x, xh, xl, 25165824 / 4);
    split_bf16<<<1728, blk, 0, stream>>>(kqv_w, wh, wl_, 1769472 / 4);
    split_bf16<<<576, blk, 0, stream>>>(proj_w, pwh, pwl, 589824 / 4);
    split_bf16<<<24, blk, 0, stream>>>(w, whb, wlb, 24576 / 4);
    // kq = x @ kqv_w[0:1536]^T  (fp32, 3-term)
    gemm256<3><<<dim3(6, 128), dim3(512), 0, stream>>>(xh, xl, wh, wl_, kqv_b, kq, nullptr, 1536, 768, 0);
    // v  = x @ kqv_w[1536:2304]^T  (bf16 out, 1-term)
    gemm256<1><<<dim3(3, 128), dim3(512), 0, stream>>>(xh, nullptr, wh + (size_t)1536 * 768, nullptr,
                                                       kqv_b + 1536, nullptr, vbf, 768, 768, 2);
    // feature maps (xh/xl dead now; kp/qp overwrite them)
    prm_exp_mfma<<<dim3(96, 64), dim3(64), 0, stream>>>(kq, whb, wlb, kp, kpsum_p, 0, 1);
    prm_exp_mfma<<<dim3(96, 64), dim3(64), 0, stream>>>(kq, whb, wlb, qp, nullptr, 768, 0);
    // kptv partials + reduce (kq dead after prm_exp)
    kptv_part<<<dim3(96, 8), blk, 0, stream>>>(vbf, kp, kptv_p);
    kptv_reduce<<<dim3(96), blk, 0, stream>>>(kptv_p, kpsum_p, kptvx);
    // normalized PV -> yh/yl (overwrites kq region)
    pv_mfma<<<dim3(96, 64), dim3(64), 0, stream>>>(qp, kptvx, yh, yl);
    // out = y @ proj_w^T + proj_b  (3-term)
    gemm256<3><<<dim3(3, 128), dim3(512), 0, stream>>>(yh, yl, pwh, pwl, proj_b, out, nullptr, 768, 768, 0);
}

// Round 7
// 602.281 us; speedup vs baseline: 1.0604x; 1.0604x over previous
//
#include <hip/hip_runtime.h>
#include <math.h>

namespace {
constexpr int cB  = 8;
constexpr int cN  = 4096;
constexpr int cC  = 768;
constexpr int cH  = 12;
constexpr int cHD = 64;
constexpr int cM  = 32;
}

typedef __attribute__((ext_vector_type(8))) short bf16x8;
typedef __attribute__((ext_vector_type(4))) float f32x4;
typedef __attribute__((ext_vector_type(16))) float f32x16;

#define BARRIER() do { asm volatile("" ::: "memory"); __builtin_amdgcn_s_barrier(); asm volatile("" ::: "memory"); } while (0)
#define WAIT_VM(N) do { asm volatile("s_waitcnt vmcnt(" #N ")" ::: "memory"); __builtin_amdgcn_sched_barrier(0); } while (0)
#define WAIT_LGKM0() do { asm volatile("s_waitcnt lgkmcnt(0)" ::: "memory"); __builtin_amdgcn_sched_barrier(0); } while (0)

__device__ __forceinline__ void async_copy16(const void* g, void* l) {
    __builtin_amdgcn_global_load_lds((const __attribute__((address_space(1))) void*)g,
                                     (__attribute__((address_space(3))) void*)l, 16, 0, 0);
}

__device__ __forceinline__ ushort f32_to_bf16_rne(float x) {
    unsigned int u = __float_as_uint(x);
    u += 0x7fffu + ((u >> 16) & 1u);
    return (ushort)(u >> 16);
}

__device__ __forceinline__ float bf16_to_f32(ushort u) {
    return __uint_as_float(((unsigned)u) << 16);
}

// RNE split: f ~= hi + lo, unbiased
__device__ __forceinline__ void split2(float f, ushort& h, ushort& l) {
    h = f32_to_bf16_rne(f);
    float r = f - bf16_to_f32(h);
    l = f32_to_bf16_rne(r);
}

__global__ __launch_bounds__(256)
void split_bf16(const float* __restrict__ in, ushort* __restrict__ hi,
                ushort* __restrict__ lo, int n4)
{
    int i = blockIdx.x * 256 + threadIdx.x;
    const int stride = gridDim.x * 256;
    for (; i < n4; i += stride) {
        float4 v = reinterpret_cast<const float4*>(in)[i];
        ushort4 h, l;
        split2(v.x, h.x, l.x);
        split2(v.y, h.y, l.y);
        split2(v.z, h.z, l.z);
        split2(v.w, h.w, l.w);
        reinterpret_cast<ushort4*>(hi)[i] = h;
        reinterpret_cast<ushort4*>(lo)[i] = l;
    }
}

// 256x256-tile GEMM, 32x32x16 MFMA, BK=32, double-buffered LDS with COUNTED
// boundary vmcnt (never 0 in steady state).  C = sum_terms Ap*Bp^T + bias.
// TERMS=3: Ah*Bh+Ah*Bl+Al*Bh;  TERMS=1: Ah*Bh.
// mode 0: Cf fp32 [M,Ndim]; mode 2: Cb bf16 v-permuted [b,h,t,d].
// Planes [256][32] bf16 (64B rows) + round-4-verified chunk XOR swizzle
// (source-side, linear gload_lds dest) -> measured 0 bank conflicts.
// Ledger: B frags are register-resident after phase 0 -> Bbuf(t&1) is free
// after barrier#1, so B(t+2) streams into it; boundary waits vmcnt(NB),
// leaving exactly B(t+2) in flight while A(t+1),B(t+1) are guaranteed landed.
template <int TERMS>
__global__ __launch_bounds__(512, 2)
void gemm256(const ushort* __restrict__ Ah, const ushort* __restrict__ Al,
             const ushort* __restrict__ Bh, const ushort* __restrict__ Bl,
             const float* __restrict__ bias,
             float* __restrict__ Cf, ushort* __restrict__ Cb,
             int Ndim, int K, int mode)
{
    constexpr int NPL = (TERMS == 3) ? 4 : 2;   // planes per tile (A..,B..)
    constexpr int PL2 = (TERMS == 3) ? 2 : 1;   // planes per operand
    __shared__ ushort smem[2 * NPL * 8192];     // 2 bufs x NPL x [256][32]
    const int tid = threadIdx.x;
    const int wave = tid >> 6, lane = tid & 63;
    const int wm = wave >> 2, wn = wave & 3;    // 2M x 4N waves, 128x64 each
    const int l31 = lane & 31, khi = lane >> 5;

    // XCD-chunked swizzle (gridDim.y == 128; nwg % 8 == 0)
    const int nwg = gridDim.x * 128;
    const int orig = blockIdx.x * 128 + blockIdx.y;
    const int swz = (orig & 7) * (nwg >> 3) + (orig >> 3);
    const int row0 = (swz & 127) << 8;
    const int col0 = (swz >> 7) << 8;

    const ushort* planes[NPL];
    planes[0] = Ah;
    if constexpr (TERMS == 3) { planes[1] = Al; planes[2] = Bh; planes[3] = Bl; }
    else                      { planes[1] = Bh; }

    // staging: plane = [256][32] = 1024 16B-chunks; thread handles 2 chunks/plane.
    // chunk ci = h2*512 + tid: row = ci>>2, source chunk cc = (ci&3)^((row>>1)&3)
    // (inverse swizzle on the GLOBAL side; LDS dest stays linear, wave-uniform).
    const ushort* gsrc[NPL][2];
    int ldst[NPL][2];
    #pragma unroll
    for (int p = 0; p < NPL; ++p)
        #pragma unroll
        for (int h2 = 0; h2 < 2; ++h2) {
            const int ci = h2 * 512 + tid;
            const int row = ci >> 2;
            const int cc = (ci & 3) ^ ((row >> 1) & 3);
            const int grow = ((p < PL2) ? row0 : col0) + row;
            gsrc[p][h2] = planes[p] + (size_t)grow * K + cc * 8;
            ldst[p][h2] = p * 8192 + h2 * 4096 + wave * 512;  // wave-uniform base
        }

    const int NT = K >> 5;
    f32x16 acc[4][2] = {};

    // prologue: A(0),B(0),A(1),B(1); wait so A(0),B(0) landed (A1,B1 stay in flight)
    #pragma unroll
    for (int p = 0; p < NPL; ++p)
        #pragma unroll
        for (int h2 = 0; h2 < 2; ++h2)
            async_copy16(gsrc[p][h2], &smem[ldst[p][h2]]);
    #pragma unroll
    for (int p = 0; p < NPL; ++p)
        #pragma unroll
        for (int h2 = 0; h2 < 2; ++h2)
            async_copy16(gsrc[p][h2] + 32, &smem[NPL * 8192 + ldst[p][h2]]);
    if constexpr (TERMS == 3) WAIT_VM(8); else WAIT_VM(4);
    BARRIER();

    for (int t = 0; t < NT; ++t) {
        const int cb = (t & 1) * NPL * 8192;
        const int nb = ((t + 1) & 1) * NPL * 8192;
        // 1. issue A(t+1) -> Abuf^1 (its last readers synced at t-1's boundary)
        if (t >= 1 && t + 1 < NT) {
            #pragma unroll
            for (int p = 0; p < PL2; ++p)
                #pragma unroll
                for (int h2 = 0; h2 < 2; ++h2)
                    async_copy16(gsrc[p][h2] + (t + 1) * 32, &smem[nb + ldst[p][h2]]);
        }
        // 2. B fragment reads (held in registers for the whole tile)
        bf16x8 fb[2][2][PL2];
        #pragma unroll
        for (int nt = 0; nt < 2; ++nt) {
            const int brow = wn * 64 + nt * 32 + l31;
            const int rsw = (brow >> 1) & 3;
            #pragma unroll
            for (int ks = 0; ks < 2; ++ks) {
                const int c = ((ks << 1) | khi) ^ rsw;
                const int off = cb + PL2 * 8192 + brow * 32 + c * 8;
                fb[nt][ks][0] = *reinterpret_cast<const bf16x8*>(&smem[off]);
                if constexpr (TERMS == 3)
                    fb[nt][ks][1] = *reinterpret_cast<const bf16x8*>(&smem[off + 8192]);
            }
        }
        // 3. all waves' B reads retired -> Bbuf(t&1) reusable
        WAIT_LGKM0();
        BARRIER();
        // 4. issue B(t+2) -> Bbuf(t&1)
        if (t + 2 < NT) {
            #pragma unroll
            for (int p = PL2; p < NPL; ++p)
                #pragma unroll
                for (int h2 = 0; h2 < 2; ++h2)
                    async_copy16(gsrc[p][h2] + (t + 2) * 32, &smem[cb + ldst[p][h2]]);
        }
        // 5. A frags per mt-pair + MFMA cluster
        #pragma unroll
        for (int mp = 0; mp < 2; ++mp) {
            bf16x8 fa[2][2][PL2];
            #pragma unroll
            for (int m2 = 0; m2 < 2; ++m2) {
                const int arow = wm * 128 + (mp * 2 + m2) * 32 + l31;
                const int rsw = (arow >> 1) & 3;
                #pragma unroll
                for (int ks = 0; ks < 2; ++ks) {
                    const int c = ((ks << 1) | khi) ^ rsw;
                    const int off = cb + arow * 32 + c * 8;
                    fa[m2][ks][0] = *reinterpret_cast<const bf16x8*>(&smem[off]);
                    if constexpr (TERMS == 3)
                        fa[m2][ks][1] = *reinterpret_cast<const bf16x8*>(&smem[off + 8192]);
                }
            }
            __builtin_amdgcn_s_setprio(1);
            #pragma unroll
            for (int term = 0; term < TERMS; ++term) {
                const int pa = (term == 2) ? 1 : 0;
                const int pb = (term == 1) ? 1 : 0;
                #pragma unroll
                for (int ks = 0; ks < 2; ++ks)
                    #pragma unroll
                    for (int m2 = 0; m2 < 2; ++m2)
                        #pragma unroll
                        for (int nt = 0; nt < 2; ++nt)
                            acc[mp * 2 + m2][nt] = __builtin_amdgcn_mfma_f32_32x32x16_bf16(
                                fa[m2][ks][pa], fb[nt][ks][pb], acc[mp * 2 + m2][nt], 0, 0, 0);
            }
            __builtin_amdgcn_s_setprio(0);
        }
        // 6. boundary: counted wait (steady: only B(t+2) left in flight)
        if (t + 2 < NT)      { if constexpr (TERMS == 3) WAIT_VM(4); else WAIT_VM(2); }
        else if (t + 1 < NT) { WAIT_VM(0); }
        if (t + 1 < NT) BARRIER();
    }

    // epilogue: C/D 32x32 layout col=lane&31, row=(reg&3)+8*(reg>>2)+4*(lane>>5)
    #pragma unroll
    for (int nt = 0; nt < 2; ++nt) {
        const int c = col0 + wn * 64 + nt * 32 + l31;
        const float bv = bias[c];
        #pragma unroll
        for (int mt = 0; mt < 4; ++mt) {
            #pragma unroll
            for (int reg = 0; reg < 16; ++reg) {
                const int rr = (reg & 3) + 8 * (reg >> 2) + 4 * khi;
                const int row = row0 + wm * 128 + mt * 32 + rr;
                const float val = acc[mt][nt][reg] + bv;
                if (mode == 0) {
                    Cf[(size_t)row * Ndim + c] = val;
                } else {
                    const int b = row >> 12, tt = row & 4095;
                    const int h = c >> 6, d = c & 63;
                    Cb[(((size_t)(b * cH + h) * cN + tt) << 6) + d] = f32_to_bf16_rne(val);
                }
            }
        }
    }
}

// Performer feature map via register-direct MFMA. One wave per (bh, 64-t block).
__global__ __launch_bounds__(64)
void prm_exp_mfma(const float* __restrict__ kq, const ushort* __restrict__ wh,
                  const ushort* __restrict__ wl, ushort* __restrict__ phi,
                  float* __restrict__ kpsum_p, int col_off, int do_sum)
{
    const int bh = blockIdx.x, tblk = blockIdx.y;
    const int b = bh / cH, h = bh % cH;
    const int t0 = tblk * 64;
    const int lane = threadIdx.x;
    const int fr = lane & 15, fk = lane >> 4;

    bf16x8 Bh2[2][2], Bl2[2][2];
    #pragma unroll
    for (int mf = 0; mf < 2; ++mf)
        #pragma unroll
        for (int kc = 0; kc < 2; ++kc) {
            size_t off = (size_t)(h * 32 + mf * 16 + fr) * 64 + kc * 32 + fk * 8;
            Bh2[mf][kc] = *reinterpret_cast<const bf16x8*>(&wh[off]);
            Bl2[mf][kc] = *reinterpret_cast<const bf16x8*>(&wl[off]);
        }

    f32x4 acc[4][2] = {};
    float xdv4[4];
    #pragma unroll
    for (int tf = 0; tf < 4; ++tf) {
        const float* krow = &kq[(size_t)(b * cN + t0 + tf * 16 + fr) * 1536 + col_off + h * 64];
        float4 f0 = *reinterpret_cast<const float4*>(&krow[fk * 8]);
        float4 f1 = *reinterpret_cast<const float4*>(&krow[fk * 8 + 4]);
        float4 f2 = *reinterpret_cast<const float4*>(&krow[32 + fk * 8]);
        float4 f3 = *reinterpret_cast<const float4*>(&krow[32 + fk * 8 + 4]);
        float xs = f0.x*f0.x + f0.y*f0.y + f0.z*f0.z + f0.w*f0.w
                 + f1.x*f1.x + f1.y*f1.y + f1.z*f1.z + f1.w*f1.w
                 + f2.x*f2.x + f2.y*f2.y + f2.z*f2.z + f2.w*f2.w
                 + f3.x*f3.x + f3.y*f3.y + f3.z*f3.z + f3.w*f3.w;
        xs += __shfl_xor(xs, 16);
        xs += __shfl_xor(xs, 32);
        xdv4[tf] = 0.5f * xs;
        bf16x8 Ah2[2], Al2[2];
        {
            float fa[8] = {f0.x,f0.y,f0.z,f0.w,f1.x,f1.y,f1.z,f1.w};
            float fb[8] = {f2.x,f2.y,f2.z,f2.w,f3.x,f3.y,f3.z,f3.w};
            #pragma unroll
            for (int j = 0; j < 8; ++j) {
                ushort hh, ll;
                split2(fa[j], hh, ll); Ah2[0][j] = (short)hh; Al2[0][j] = (short)ll;
                split2(fb[j], hh, ll); Ah2[1][j] = (short)hh; Al2[1][j] = (short)ll;
            }
        }
        #pragma unroll
        for (int kc = 0; kc < 2; ++kc)
            #pragma unroll
            for (int mf = 0; mf < 2; ++mf) {
                acc[tf][mf] = __builtin_amdgcn_mfma_f32_16x16x32_bf16(Ah2[kc], Bh2[mf][kc], acc[tf][mf], 0, 0, 0);
                acc[tf][mf] = __builtin_amdgcn_mfma_f32_16x16x32_bf16(Ah2[kc], Bl2[mf][kc], acc[tf][mf], 0, 0, 0);
                acc[tf][mf] = __builtin_amdgcn_mfma_f32_16x16x32_bf16(Al2[kc], Bh2[mf][kc], acc[tf][mf], 0, 0, 0);
            }
    }

    const float rsm = 0.17677669529663687f;  // 1/sqrt(32)
    float sm0 = 0.f, sm1 = 0.f;
    #pragma unroll
    for (int tf = 0; tf < 4; ++tf) {
        #pragma unroll
        for (int j = 0; j < 4; ++j) {
            const int rloc = (lane >> 4) * 4 + j;
            const float xdv = __shfl(xdv4[tf], (lane & 48) | rloc);
            const int t = t0 + tf * 16 + rloc;
            float e0 = __expf(acc[tf][0][j] - xdv) * rsm;
            float e1 = __expf(acc[tf][1][j] - xdv) * rsm;
            phi[((size_t)bh * cN + t) * cM + fr]      = f32_to_bf16_rne(e0);
            phi[((size_t)bh * cN + t) * cM + 16 + fr] = f32_to_bf16_rne(e1);
            sm0 += e0; sm1 += e1;
        }
    }
    if (do_sum) {
        sm0 += __shfl_xor(sm0, 16); sm0 += __shfl_xor(sm0, 32);
        sm1 += __shfl_xor(sm1, 16); sm1 += __shfl_xor(sm1, 32);
        if (lane < 16) {
            kpsum_p[((size_t)bh * 64 + tblk) * cM + lane]      = sm0;
            kpsum_p[((size_t)bh * 64 + tblk) * cM + 16 + lane] = sm1;
        }
    }
}

// kptv partials: kptv_p[c][bh][d][m] over 32-t slices; c = chunk*2+half, 16 total
__global__ __launch_bounds__(256, 4)
void kptv_part(const ushort* __restrict__ vbf, const ushort* __restrict__ kp,
               float* __restrict__ kptv_p)
{
    const int bh = blockIdx.x, chunk = blockIdx.y;
    __shared__ float vl[64][68];
    __shared__ float kl[64][36];
    const int tid = threadIdx.x;
    const int half = tid >> 7;
    const int dg = (tid >> 3) & 15;
    const int mg = tid & 7;
    float acc[4][4] = {};
    for (int tile = 0; tile < 8; ++tile) {
        const int tb = chunk * 512 + tile * 64;
        #pragma unroll
        for (int i = 0; i < 2; ++i) {
            int idx = i * 256 + tid;
            int row = idx >> 3, seg = idx & 7;
            bf16x8 vv = *reinterpret_cast<const bf16x8*>(&vbf[((size_t)bh * cN + tb + row) * 64 + seg * 8]);
            float4 lo4 = make_float4(bf16_to_f32((ushort)vv[0]), bf16_to_f32((ushort)vv[1]),
                                     bf16_to_f32((ushort)vv[2]), bf16_to_f32((ushort)vv[3]));
            float4 hi4 = make_float4(bf16_to_f32((ushort)vv[4]), bf16_to_f32((ushort)vv[5]),
                                     bf16_to_f32((ushort)vv[6]), bf16_to_f32((ushort)vv[7]));
            *reinterpret_cast<float4*>(&vl[row][seg * 8])     = lo4;
            *reinterpret_cast<float4*>(&vl[row][seg * 8 + 4]) = hi4;
        }
        {
            int row = tid >> 2, seg = tid & 3;
            bf16x8 vv = *reinterpret_cast<const bf16x8*>(&kp[((size_t)bh * cN + tb + row) * 32 + seg * 8]);
            float4 lo4 = make_float4(bf16_to_f32((ushort)vv[0]), bf16_to_f32((ushort)vv[1]),
                                     bf16_to_f32((ushort)vv[2]), bf16_to_f32((ushort)vv[3]));
            float4 hi4 = make_float4(bf16_to_f32((ushort)vv[4]), bf16_to_f32((ushort)vv[5]),
                                     bf16_to_f32((ushort)vv[6]), bf16_to_f32((ushort)vv[7]));
            *reinterpret_cast<float4*>(&kl[row][seg * 8])     = lo4;
            *reinterpret_cast<float4*>(&kl[row][seg * 8 + 4]) = hi4;
        }
        __syncthreads();
        for (int t = 0; t < 32; ++t) {
            const int tt = half * 32 + t;
            float4 av = *reinterpret_cast<const float4*>(&vl[tt][dg * 4]);
            float4 bv = *reinterpret_cast<const float4*>(&kl[tt][mg * 4]);
            float a4[4] = {av.x, av.y, av.z, av.w};
            float b4[4] = {bv.x, bv.y, bv.z, bv.w};
            #pragma unroll
            for (int i = 0; i < 4; ++i)
                #pragma unroll
                for (int j = 0; j < 4; ++j)
                    acc[i][j] = fmaf(a4[i], b4[j], acc[i][j]);
        }
        __syncthreads();
    }
    float* outp = &kptv_p[(((size_t)chunk * 2 + half) * 96 + bh) * 2048];
    #pragma unroll
    for (int i = 0; i < 4; ++i)
        *reinterpret_cast<float4*>(&outp[(dg * 4 + i) * 32 + mg * 4]) =
            make_float4(acc[i][0], acc[i][1], acc[i][2], acc[i][3]);
}

// reduce partials -> kptvx bf16 [bh][80][32]: rows 0..63 kptv, row 64 kpsum, 65..79 zero
__global__ __launch_bounds__(256)
void kptv_reduce(const float* __restrict__ kptv_p, const float* __restrict__ kpsum_p,
                 ushort* __restrict__ kptvx)
{
    const int bh = blockIdx.x, tid = threadIdx.x;
    for (int l = tid; l < 2048; l += 256) {
        float s = 0.f;
        #pragma unroll
        for (int c = 0; c < 16; ++c) s += kptv_p[((size_t)c * 96 + bh) * 2048 + l];
        kptvx[(size_t)bh * 2560 + l] = f32_to_bf16_rne(s);
    }
    if (tid < 32) {
        float s = 0.f;
        #pragma unroll
        for (int c = 0; c < 64; ++c) s += kpsum_p[((size_t)bh * 64 + c) * cM + tid];
        kptvx[(size_t)bh * 2560 + 64 * 32 + tid] = f32_to_bf16_rne(s);
    }
    for (int l = tid; l < 480; l += 256)
        kptvx[(size_t)bh * 2560 + 65 * 32 + l] = 0;
}

// y = (qp . kptv) / (qp . kpsum + eps) via one MFMA pass (D appended as B-row 64)
__global__ __launch_bounds__(64)
void pv_mfma(const ushort* __restrict__ qp, const ushort* __restrict__ kptvx,
             ushort* __restrict__ yh, ushort* __restrict__ yl)
{
    const int bh = blockIdx.x, tblk = blockIdx.y;
    const int b = bh / cH, h = bh % cH;
    const int t0 = tblk * 64;
    const int lane = threadIdx.x;
    const int fr = lane & 15, fk = lane >> 4;
    bf16x8 Bf[5];
    #pragma unroll
    for (int nf = 0; nf < 5; ++nf)
        Bf[nf] = *reinterpret_cast<const bf16x8*>(&kptvx[(size_t)bh * 2560 + (nf * 16 + fr) * 32 + fk * 8]);
    f32x4 acc[4][5] = {};
    #pragma unroll
    for (int tf = 0; tf < 4; ++tf) {
        bf16x8 Af = *reinterpret_cast<const bf16x8*>(&qp[((size_t)bh * cN + t0 + tf * 16 + fr) * cM + fk * 8]);
        #pragma unroll
        for (int nf = 0; nf < 5; ++nf)
            acc[tf][nf] = __builtin_amdgcn_mfma_f32_16x16x32_bf16(Af, Bf[nf], acc[tf][nf], 0, 0, 0);
    }
    #pragma unroll
    for (int tf = 0; tf < 4; ++tf) {
        #pragma unroll
        for (int j = 0; j < 4; ++j) {
            const int rloc = (lane >> 4) * 4 + j;
            const int t = t0 + tf * 16 + rloc;
            const float Dv = __shfl(acc[tf][4][j], lane & 48) + 1e-8f;
            const float rD = 1.0f / Dv;
            #pragma unroll
            for (int nf = 0; nf < 4; ++nf) {
                float yv = acc[tf][nf][j] * rD;
                ushort hh, ll; split2(yv, hh, ll);
                size_t oa = (size_t)(b * cN + t) * cC + h * 64 + nf * 16 + fr;
                yh[oa] = hh; yl[oa] = ll;
            }
        }
    }
}

extern "C" void kernel_launch(void* const* d_in, const int* in_sizes, int n_in,
                              void* d_out, int out_size, void* d_ws, size_t ws_size,
                              hipStream_t stream)
{
    const float* x      = (const float*)d_in[0];
    const float* kqv_w  = (const float*)d_in[1];
    const float* kqv_b  = (const float*)d_in[2];
    const float* proj_w = (const float*)d_in[3];
    const float* proj_b = (const float*)d_in[4];
    const float* w      = (const float*)d_in[5];

    char* wsb = (char*)d_ws;
    float*  kq   = (float*)(wsb);                  // [32768,1536] fp32, 201,326,592 B
    ushort* yh   = (ushort*)(wsb);                 // aliases kq after dead
    ushort* yl   = (ushort*)(wsb + 50331648);
    ushort* vbf  = (ushort*)(wsb + 201326592);     // [96][4096][64] bf16
    ushort* wh   = (ushort*)(wsb + 251658240);     // kqv_w hi
    ushort* wl_  = (ushort*)(wsb + 255197184);     // kqv_w lo
    ushort* pwh  = (ushort*)(wsb + 258736128);     // proj_w hi
    ushort* pwl  = (ushort*)(wsb + 259915776);     // proj_w lo
    ushort* whb  = (ushort*)(wsb + 261095424);     // w hi (bf16)
    ushort* wlb  = (ushort*)(wsb + 261144576);     // w lo

    char* ob = (char*)d_out;
    ushort* xh      = (ushort*)ob;                 // x hi plane
    ushort* xl      = (ushort*)(ob + 50331648);    // x lo plane
    ushort* kp      = (ushort*)ob;                 // [96][4096][32] bf16 (after xh dead)
    ushort* qp      = (ushort*)(ob + 25165824);
    float*  kptv_p  = (float*)(ob + 50331648);     // [16][96][2048] fp32 (after xl dead)
    float*  kpsum_p = (float*)(ob + 62914560);     // [96][64][32] fp32
    ushort* kptvx   = (ushort*)(ob + 63700992);    // [96][80][32] bf16
    float*  out     = (float*)d_out;

    dim3 blk(256);
    // splits (RNE hi/lo planes)
    split_bf16<<<2048, blk, 0, stream>>>(x, xh, xl, 25165824 / 4);
    split_bf16<<<1728, blk, 0, stream>>>(kqv_w, wh, wl_, 1769472 / 4);
    split_bf16<<<576, blk, 0, stream>>>(proj_w, pwh, pwl, 589824 / 4);
    split_bf16<<<24, blk, 0, stream>>>(w, whb, wlb, 24576 / 4);
    // kq = x @ kqv_w[0:1536]^T  (fp32, 3-term)
    gemm256<3><<<dim3(6, 128), dim3(512), 0, stream>>>(xh, xl, wh, wl_, kqv_b, kq, nullptr, 1536, 768, 0);
    // v  = x @ kqv_w[1536:2304]^T  (bf16 out, 1-term)
    gemm256<1><<<dim3(3, 128), dim3(512), 0, stream>>>(xh, nullptr, wh + (size_t)1536 * 768, nullptr,
                                                       kqv_b + 1536, nullptr, vbf, 768, 768, 2);
    // feature maps (xh/xl dead now; kp/qp overwrite them)
    prm_exp_mfma<<<dim3(96, 64), dim3(64), 0, stream>>>(kq, whb, wlb, kp, kpsum_p, 0, 1);
    prm_exp_mfma<<<dim3(96, 64), dim3(64), 0, stream>>>(kq, whb, wlb, qp, nullptr, 768, 0);
    // kptv partials + reduce (kq dead after prm_exp)
    kptv_part<<<dim3(96, 8), blk, 0, stream>>>(vbf, kp, kptv_p);
    kptv_reduce<<<dim3(96), blk, 0, stream>>>(kptv_p, kpsum_p, kptvx);
    // normalized PV -> yh/yl (overwrites kq region)
    pv_mfma<<<dim3(96, 64), dim3(64), 0, stream>>>(qp, kptvx, yh, yl);
    // out = y @ proj_w^T + proj_b  (3-term)
    gemm256<3><<<dim3(3, 128), dim3(512), 0, stream>>>(yh, yl, pwh, pwl, proj_b, out, nullptr, 768, 768, 0);
}